// Round 9
// baseline (327.834 us; speedup 1.0000x reference)
//
#include <hip/hip_runtime.h>
#include <math.h>

#define DCH 384
#define NH 12
#define CH 32
#define SS 128
#define LL 256
#define NPOS 32768        // SS*LL
#define THREE_D 1152

typedef _Float16 f16_t;
typedef _Float16 f16x4 __attribute__((ext_vector_type(4)));
typedef _Float16 f16x8 __attribute__((ext_vector_type(8)));
typedef float f32x4 __attribute__((ext_vector_type(4)));

// async global->LDS, 16B per lane.
#define GLD16(gptr, lptr) __builtin_amdgcn_global_load_lds( \
    (const __attribute__((address_space(1))) unsigned int*)(gptr), \
    (__attribute__((address_space(3))) unsigned int*)(lptr), 16, 0, 0)

#define WAVE_LDS_FENCE() __asm__ volatile("s_waitcnt lgkmcnt(0)" ::: "memory")

// ---------------------------------------------------------------------------
// fp32 -> fp16 elementwise (weights, layout preserved). n4 = count/4.
// ---------------------------------------------------------------------------
__global__ __launch_bounds__(256) void conv_w(const float* __restrict__ in,
                                              f16_t* __restrict__ out, int n4) {
    int i = blockIdx.x * 256 + threadIdx.x;
    if (i < n4) {
        float4 v = ((const float4*)in)[i];
        unsigned short u0 = __builtin_bit_cast(unsigned short, (f16_t)v.x);
        unsigned short u1 = __builtin_bit_cast(unsigned short, (f16_t)v.y);
        unsigned short u2 = __builtin_bit_cast(unsigned short, (f16_t)v.z);
        unsigned short u3 = __builtin_bit_cast(unsigned short, (f16_t)v.w);
        uint2 r;
        r.x = (unsigned)u0 | ((unsigned)u1 << 16);
        r.y = (unsigned)u2 | ((unsigned)u3 << 16);
        ((uint2*)out)[i] = r;
    }
}

// ---------------------------------------------------------------------------
// zero 2*NPOS floats (SUM/SQ accumulators).
// ---------------------------------------------------------------------------
__global__ __launch_bounds__(256) void zero_stats(float* __restrict__ p) {
    ((float4*)p)[blockIdx.x * 256 + threadIdx.x] = (float4){0.f, 0.f, 0.f, 0.f};
}

// ---------------------------------------------------------------------------
// fp32 [DCH][NPOS] -> fp16 [NPOS][DCH]  (transpose + convert, 64x64 tiles)
// ---------------------------------------------------------------------------
__global__ __launch_bounds__(256) void conv_xT(const float* __restrict__ in,
                                               f16_t* __restrict__ outp) {
    __shared__ float tile[64][65];
    const int p0 = blockIdx.x * 64;
    const int k0 = blockIdx.y * 64;
    const int tx = threadIdx.x & 63, ty = threadIdx.x >> 6;  // ty 0..3
#pragma unroll
    for (int i = 0; i < 16; ++i)
        tile[ty * 16 + i][tx] = in[(size_t)(k0 + ty * 16 + i) * NPOS + p0 + tx];
    __syncthreads();
    const int pr = threadIdx.x >> 2;   // 0..63 output row (p)
    const int cg = threadIdx.x & 3;    // 16-col group (k)
    union { uint4 v[2]; unsigned int u[8]; } res;
#pragma unroll
    for (int j = 0; j < 8; ++j) {
        unsigned short lo = __builtin_bit_cast(unsigned short, (f16_t)tile[cg * 16 + 2 * j][pr]);
        unsigned short hi = __builtin_bit_cast(unsigned short, (f16_t)tile[cg * 16 + 2 * j + 1][pr]);
        res.u[j] = (unsigned)lo | ((unsigned)hi << 16);
    }
    uint4* dst = (uint4*)&outp[(size_t)(p0 + pr) * DCH + k0 + cg * 16];
    dst[0] = res.v[0];
    dst[1] = res.v[1];
}

// ---------------------------------------------------------------------------
// fp16 MFMA GEMM (R5/R8 structure: whole 128x384 A panel in LDS once,
// barrier-free K-loop, B streamed global->reg, acc[8][2], XCD swizzle,
// conflict-free row&15 key).
// R9: B prefetch depth 2 -> 4 (breg[5][2], issue tile t+4). Load-to-use
//     distance ~2 steps (~200-240cy, marginal vs L2 latency) -> ~4 steps
//     (~400-480cy, covers L2 with margin). +16 VGPR; occupancy unchanged
//     (LDS-bound). Single-change probe of the exposed-latency hypothesis.
// ---------------------------------------------------------------------------
__global__ __launch_bounds__(512) void qkv_gemm_f16(
        const f16_t* __restrict__ Wh,    // [THREE_D][DCH]
        const float* __restrict__ bias,  // [THREE_D]
        const f16_t* __restrict__ Xp,    // [NPOS][DCH]
        f16_t* __restrict__ Yq, f16_t* __restrict__ Yk, f16_t* __restrict__ Yv)
{
    __shared__ f16_t sha[128 * 384];   // 96 KB; [row][slot^key] 16B slots
    const int tid  = threadIdx.x;
    const int lane = tid & 63;
    const int wave = tid >> 6;         // 0..7

    // Bijective XCD swizzle: nwg = 9*128 = 1152 = 8 * 144.
    const int hwid = blockIdx.y * 9 + blockIdx.x;      // x fastest in dispatch
    const int nid  = (hwid & 7) * 144 + (hwid >> 3);
    const int ot   = nid % 9;                           // 0..8
    const int pt   = nid / 9;                           // 0..127
    const int o0 = ot * 128;
    const int p0 = pt * 256;

    const int mrow = lane & 15;
    const int kgq  = lane >> 4;        // k-quad 0..3

    // ---- stage whole A panel (128 rows x 48 slots of 16B), once ----
    // slot s of row holds k-group g = s ^ (row & 15) (XOR involution).
#pragma unroll
    for (int j = 0; j < 12; ++j) {
        const int ibase = (wave * 12 + j) * 64;   // wave-uniform slot base
        const int i = ibase + lane;
        const int row = i / 48;
        const int s = i - row * 48;
        const int g = s ^ (row & 15);
        GLD16(Wh + (size_t)(o0 + row) * DCH + g * 8, sha + (size_t)ibase * 8);
    }

    // ---- B reg-stream bases (per-lane). Wave covers p rows wave*32..+31. ----
    const f16_t* bp0 = Xp + (size_t)(p0 + wave * 32 + mrow) * DCH + kgq * 8;
    const f16_t* bp1 = bp0 + (size_t)16 * DCH;

    f32x4 acc[8][2] = {};
    f16x8 breg[5][2];

    // prefetch B tiles 0..3 while A staging drains (depth-4 pipeline fill)
#pragma unroll
    for (int t = 0; t < 4; ++t) {
        breg[t][0] = *(const f16x8*)(bp0 + t * 32);
        breg[t][1] = *(const f16x8*)(bp1 + t * 32);
    }

    __syncthreads();   // the ONLY barrier: A panel visible to all waves

    constexpr int NK = DCH / 32;       // 12
#pragma unroll
    for (int t = 0; t < NK; ++t) {
        if (t + 4 < NK) {
            breg[(t + 4) % 5][0] = *(const f16x8*)(bp0 + (t + 4) * 32);
            breg[(t + 4) % 5][1] = *(const f16x8*)(bp1 + (t + 4) * 32);
        }
        // read rows are mi*16 + mrow -> key = mrow for all mi
        const int soff = ((t * 4 + kgq) ^ mrow) * 8;
#pragma unroll
        for (int mi = 0; mi < 8; ++mi) {
            const f16x8 a = *(const f16x8*)(
                sha + (size_t)(mi * 16 + mrow) * DCH + soff);
            acc[mi][0] = __builtin_amdgcn_mfma_f32_16x16x32_f16(
                a, breg[t % 5][0], acc[mi][0], 0, 0, 0);
            acc[mi][1] = __builtin_amdgcn_mfma_f32_16x16x32_f16(
                a, breg[t % 5][1], acc[mi][1], 0, 0, 0);
        }
    }

    // C/D layout: col = lane&15 (p), row = (lane>>4)*4 + r (o)
    const int col = lane & 15;
    const int rq4 = (lane >> 4) * 4;
    const int qkv = ot / 3;     // 0=q 1=k 2=v
    const int grp = ot % 3;     // 128-block within the qkv group

    if (qkv < 2) {
        f16_t* Yt = (qkv == 0) ? Yq : Yk;
#pragma unroll
        for (int mi = 0; mi < 8; ++mi) {
            const int h  = grp * 4 + (mi >> 1);
            const int cb = (mi & 1) * 16 + rq4;               // c base; +r consecutive
            const int ob = o0 + mi * 16 + rq4;                // bias base
            const float b0 = bias[ob], b1 = bias[ob + 1];
            const float b2 = bias[ob + 2], b3 = bias[ob + 3];
#pragma unroll
            for (int ni = 0; ni < 2; ++ni) {
                const int p = p0 + wave * 32 + ni * 16 + col;
                union { uint2 u; f16_t h4[4]; } w;
                w.h4[0] = (f16_t)(acc[mi][ni][0] + b0);
                w.h4[1] = (f16_t)(acc[mi][ni][1] + b1);
                w.h4[2] = (f16_t)(acc[mi][ni][2] + b2);
                w.h4[3] = (f16_t)(acc[mi][ni][3] + b3);
                *(uint2*)(Yt + ((size_t)h * NPOS + p) * CH + cb) = w.u;
            }
        }
    } else {
#pragma unroll
        for (int mi = 0; mi < 8; ++mi) {
#pragma unroll
            for (int r = 0; r < 4; ++r) {
                const int cg = grp * 128 + mi * 16 + rq4 + r;  // 0..383
                const float br = bias[768 + cg];
#pragma unroll
                for (int ni = 0; ni < 2; ++ni) {
                    const int p = p0 + wave * 32 + ni * 16 + col;
                    Yv[(size_t)cg * NPOS + p] = (f16_t)(acc[mi][ni][r] + br);
                }
            }
        }
    }
}

// ---------------------------------------------------------------------------
// MFMA axial attention, LDS-staged K/V. Fused LN partial stats.
// Residual always fp16 [pos][DCH]. AROW selects A-output layout:
//   AROW=true  (stage 1): A[pos][DCH] coalesced -> row-permute norm_xT.
//   AROW=false (stage 2): A[d][NPOS] -> coalesced norm_transpose.
// ---------------------------------------------------------------------------
template <int SEQ, bool AROW>
__global__ __launch_bounds__(256) void mfma_attn(
        const f16_t* __restrict__ Yq, const f16_t* __restrict__ Yk,
        const f16_t* __restrict__ Yv, const f16_t* __restrict__ Xh,
        f16_t* __restrict__ R, float* __restrict__ SUM, float* __restrict__ SQ)
{
    constexpr int JT  = SEQ / 16;    // j-tiles
    constexpr int NIT = SEQ / 64;    // i-tiles per wave
    constexpr int PST = SEQ + 8;     // padded P row stride (fp16 units)
    constexpr int VST = SEQ + 8;     // padded V row stride
    __shared__ f16_t Ks[SEQ * CH];       // [pos][ch-swz]
    __shared__ f16_t Vs[CH * VST];       // [ch][pos]
    __shared__ f16_t pb[4][16 * PST];
    const int tid  = threadIdx.x;
    const int lane = tid & 63;
    const int wave = tid >> 6;
    const int col = lane & 15, quad = lane >> 4;
    const int h = blockIdx.x % NH;
    const size_t pbase = (size_t)(blockIdx.x / NH) * SEQ;

    const f16_t* qg = Yq + ((size_t)h * NPOS + pbase) * CH;
    const f16_t* kg = Yk + ((size_t)h * NPOS + pbase) * CH;
    const f16_t* vg = Yv + (size_t)h * CH * NPOS + pbase;
    f16_t* mypb = pb[wave];

    // ---- stage K (async, linear dest; source k-group pre-swizzled) ----
    {
        const int ksw = (lane & 3) ^ ((lane >> 3) & 3);
        const int lrow32 = (lane >> 2) * 32;
#pragma unroll
        for (int i = 0; i < SEQ / 64; ++i) {
            const int off = (wave * (SEQ / 64) + i) * 512;  // f16 units
            GLD16(kg + off + lrow32 + ksw * 8, Ks + off);
        }
    }
    // ---- stage V^T (coalesced float4, padded rows) ----
    {
        constexpr int CPR = SEQ / 8;
        const int vch = tid % CPR;
        const int vr0 = tid / CPR;
#pragma unroll
        for (int r = vr0; r < CH; r += 256 / CPR)
            *(float4*)(Vs + r * VST + vch * 8) =
                *(const float4*)(vg + (size_t)r * NPOS + vch * 8);
    }
    __syncthreads();

    const int kq8 = (quad ^ ((col >> 1) & 3)) * 8;   // swizzled Ks k-slot

    for (int it = 0; it < NIT; ++it) {
        const int i0 = (wave * NIT + it) * 16;
        const f16x8 qf = *(const f16x8*)(qg + (size_t)(i0 + col) * CH + quad * 8);
        f32x4 st[JT];
#pragma unroll
        for (int mt = 0; mt < JT; ++mt) {
            f16x8 kf = *(const f16x8*)(Ks + (mt * 16 + col) * CH + kq8);
            st[mt] = __builtin_amdgcn_mfma_f32_16x16x32_f16(kf, qf, (f32x4){0.f, 0.f, 0.f, 0.f}, 0, 0, 0);
        }
        float sum = 0.f;
#pragma unroll
        for (int mt = 0; mt < JT; ++mt)
#pragma unroll
            for (int r = 0; r < 4; ++r) {
                st[mt][r] = __expf(st[mt][r]);
                sum += st[mt][r];
            }
        sum += __shfl_xor(sum, 16, 64);
        sum += __shfl_xor(sum, 32, 64);
        const float inv = 1.f / sum;
#pragma unroll
        for (int mt = 0; mt < JT; ++mt) {
            union { uint2 u; f16_t h4[4]; } w;
            w.h4[0] = (f16_t)(st[mt][0] * inv);
            w.h4[1] = (f16_t)(st[mt][1] * inv);
            w.h4[2] = (f16_t)(st[mt][2] * inv);
            w.h4[3] = (f16_t)(st[mt][3] * inv);
            *(uint2*)(mypb + col * PST + mt * 16 + quad * 4) = w.u;
        }
        WAVE_LDS_FENCE();

        f32x4 o0a = {0.f, 0.f, 0.f, 0.f}, o0b = {0.f, 0.f, 0.f, 0.f};
        f32x4 o1a = {0.f, 0.f, 0.f, 0.f}, o1b = {0.f, 0.f, 0.f, 0.f};
#pragma unroll
        for (int ks = 0; ks < SEQ / 32; ks += 2) {
            f16x8 pf0 = *(const f16x8*)(mypb + col * PST + ks * 32 + quad * 8);
            f16x8 pf1 = *(const f16x8*)(mypb + col * PST + (ks + 1) * 32 + quad * 8);
            f16x8 va0 = *(const f16x8*)(Vs + col * VST + ks * 32 + quad * 8);
            f16x8 va1 = *(const f16x8*)(Vs + col * VST + (ks + 1) * 32 + quad * 8);
            f16x8 vb0 = *(const f16x8*)(Vs + (16 + col) * VST + ks * 32 + quad * 8);
            f16x8 vb1 = *(const f16x8*)(Vs + (16 + col) * VST + (ks + 1) * 32 + quad * 8);
            o0a = __builtin_amdgcn_mfma_f32_16x16x32_f16(va0, pf0, o0a, 0, 0, 0);
            o0b = __builtin_amdgcn_mfma_f32_16x16x32_f16(va1, pf1, o0b, 0, 0, 0);
            o1a = __builtin_amdgcn_mfma_f32_16x16x32_f16(vb0, pf0, o1a, 0, 0, 0);
            o1b = __builtin_amdgcn_mfma_f32_16x16x32_f16(vb1, pf1, o1b, 0, 0, 0);
        }
        const f32x4 ot0 = o0a + o0b;
        const f32x4 ot1 = o1a + o1b;

        const size_t pos = pbase + i0 + col;
        const f16x4 xa = *(const f16x4*)(Xh + pos * DCH + h * CH + quad * 4);
        const f16x4 xb = *(const f16x4*)(Xh + pos * DCH + h * CH + 16 + quad * 4);
        float a0[4], a1[4];
#pragma unroll
        for (int r = 0; r < 4; ++r) {
            a0[r] = (float)xa[r] + ot0[r];
            a1[r] = (float)xb[r] + ot1[r];
        }
        float psum = 0.f, psq = 0.f;
#pragma unroll
        for (int r = 0; r < 4; ++r) {
            psum += a0[r] + a1[r];
            psq  += a0[r] * a0[r] + a1[r] * a1[r];
        }
        if constexpr (AROW) {
            f16x4 w0, w1;
#pragma unroll
            for (int r = 0; r < 4; ++r) {
                w0[r] = (f16_t)a0[r];
                w1[r] = (f16_t)a1[r];
            }
            *(f16x4*)(R + pos * DCH + h * CH + quad * 4)      = w0;
            *(f16x4*)(R + pos * DCH + h * CH + 16 + quad * 4) = w1;
        } else {
#pragma unroll
            for (int r = 0; r < 4; ++r) {
                R[(size_t)(h * CH + quad * 4 + r) * NPOS + pos]      = (f16_t)a0[r];
                R[(size_t)(h * CH + 16 + quad * 4 + r) * NPOS + pos] = (f16_t)a1[r];
            }
        }
        // cross-quad reduce (col fixed): full 32-channel partial for this head
        psum += __shfl_xor(psum, 16, 64);
        psum += __shfl_xor(psum, 32, 64);
        psq  += __shfl_xor(psq, 16, 64);
        psq  += __shfl_xor(psq, 32, 64);
        if (quad == 0) {
            atomicAdd(&SUM[pos], psum);
            atomicAdd(&SQ[pos], psq);
        }
    }
}

// ---------------------------------------------------------------------------
// norm_xT: pure row-permute LN-apply. A fp16 [pos1 = s*LL+l][DCH] ->
// Xp fp16 [pos2 = l*SS+s][DCH]. No transpose, no LDS.
// ---------------------------------------------------------------------------
__global__ __launch_bounds__(256) void norm_xT(
        const f16_t* __restrict__ A, const float* __restrict__ SUM,
        const float* __restrict__ SQ, const float* __restrict__ w,
        const float* __restrict__ b, f16_t* __restrict__ Xp) {
    const int row = blockIdx.x * 64 + (threadIdx.x >> 2);   // pos1
    const int c4 = threadIdx.x & 3;
    const int s = row >> 8, l = row & (LL - 1);             // pos1 = s*LL + l
    const int po = l * SS + s;                              // pos2
    const float m  = SUM[row] * (1.f / DCH);
    const float rs = rsqrtf(SQ[row] * (1.f / DCH) - m * m + 1e-5f);
    const f16_t* ar = A + (size_t)row * DCH;
    f16_t* xr = Xp + (size_t)po * DCH;
#pragma unroll
    for (int j = 0; j < 12; ++j) {
        const int d0 = c4 * 8 + j * 32;
        f16x8 v = *(const f16x8*)(ar + d0);
        const float4 w0 = *(const float4*)(w + d0);
        const float4 w1 = *(const float4*)(w + d0 + 4);
        const float4 b0 = *(const float4*)(b + d0);
        const float4 b1 = *(const float4*)(b + d0 + 4);
        f16x8 o;
        o[0] = (f16_t)(((float)v[0] - m) * rs * w0.x + b0.x);
        o[1] = (f16_t)(((float)v[1] - m) * rs * w0.y + b0.y);
        o[2] = (f16_t)(((float)v[2] - m) * rs * w0.z + b0.z);
        o[3] = (f16_t)(((float)v[3] - m) * rs * w0.w + b0.w);
        o[4] = (f16_t)(((float)v[4] - m) * rs * w1.x + b1.x);
        o[5] = (f16_t)(((float)v[5] - m) * rs * w1.y + b1.y);
        o[6] = (f16_t)(((float)v[6] - m) * rs * w1.z + b1.z);
        o[7] = (f16_t)(((float)v[7] - m) * rs * w1.w + b1.w);
        *(f16x8*)(xr + d0) = o;
    }
}

// ---------------------------------------------------------------------------
// Final: normalize (inline mu/rs from SUM/SQ) + per-channel transpose.
// in is fp16 A [d][pos2-domain]; out fp32. (Both sides coalesced.)
// ---------------------------------------------------------------------------
__global__ __launch_bounds__(256) void norm_transpose(
        const f16_t* __restrict__ in, const float* __restrict__ SUM,
        const float* __restrict__ SQ, const float* __restrict__ w,
        const float* __restrict__ b, float* __restrict__ out, int Rr, int Cc) {
    __shared__ float tile[32][33];
    const int ntc = Cc >> 5, ntr = Rr >> 5;
    int tc = blockIdx.x % ntc;
    int tr = (blockIdx.x / ntc) % ntr;
    int d = blockIdx.x / (ntc * ntr);
    int tx = threadIdx.x & 31, ty = threadIdx.x >> 5;  // ty 0..7
    const f16_t* ip = in + (size_t)d * Rr * Cc;
    float* op = out + (size_t)d * Rr * Cc;
    const float wd = w[d], bd = b[d];
#pragma unroll
    for (int i = 0; i < 32; i += 8) {
        const int r = tr * 32 + ty + i;
        const int c = tc * 32 + tx;
        const int pos = r * Cc + c;
        const float m  = SUM[pos] * (1.f / DCH);
        const float rs = rsqrtf(SQ[pos] * (1.f / DCH) - m * m + 1e-5f);
        float v = (float)ip[(size_t)r * Cc + c];
        tile[ty + i][tx] = (v - m) * rs * wd + bd;
    }
    __syncthreads();
#pragma unroll
    for (int i = 0; i < 32; i += 8)
        op[(size_t)(tc * 32 + ty + i) * Rr + tr * 32 + tx] = tile[tx][ty + i];
}

extern "C" void kernel_launch(void* const* d_in, const int* in_sizes, int n_in,
                              void* d_out, int out_size, void* d_ws, size_t ws_size,
                              hipStream_t stream) {
    const float* x     = (const float*)d_in[0];
    const float* row_w = (const float*)d_in[1];
    const float* row_b = (const float*)d_in[2];
    const float* col_w = (const float*)d_in[3];
    const float* col_b = (const float*)d_in[4];
    const float* ln1_w = (const float*)d_in[5];
    const float* ln1_b = (const float*)d_in[6];
    const float* ln2_w = (const float*)d_in[7];
    const float* ln2_b = (const float*)d_in[8];
    float* out = (float*)d_out;

    char* ws = (char*)d_ws;
    const size_t ysz = (size_t)NH * NPOS * CH * 2;   // 25.2 MB (== DCH*NPOS*2)
    const size_t abytes = (size_t)DCH * NPOS * 4;    // region kept (A uses half)
    f16_t* Yq = (f16_t*)ws;
    f16_t* Yk = (f16_t*)(ws + ysz);
    f16_t* Yv = (f16_t*)(ws + 2 * ysz);
    f16_t* A  = (f16_t*)(ws + 3 * ysz);              // fp16, 25.2 MB
    f16_t* Xp = (f16_t*)(ws + 3 * ysz + abytes);
    f16_t* Wh = (f16_t*)(ws + 3 * ysz + abytes + ysz);
    float* SUMB = (float*)(ws + 3 * ysz + abytes + ysz + (1 << 21));
    float* SQB  = SUMB + NPOS;

    dim3 ggrid(THREE_D / 128, NPOS / 256);   // x = o-tile (9), y = p-tile (128)
    const int wn4 = THREE_D * DCH / 4;
    dim3 cgrid(NPOS / 64, DCH / 64);

    // ---- stage 1: row attention (attend over L within each row s) ----
    conv_w<<<(wn4 + 255) / 256, 256, 0, stream>>>(row_w, Wh, wn4);
    conv_xT<<<cgrid, 256, 0, stream>>>(x, Xp);
    zero_stats<<<2 * NPOS / 1024, 256, 0, stream>>>(SUMB);
    qkv_gemm_f16<<<ggrid, 512, 0, stream>>>(Wh, row_b, Xp, Yq, Yk, Yv);
    // A = Xp + row_out, row-major [pos1][DCH]
    mfma_attn<LL, true><<<NH * SS, 256, 0, stream>>>(Yq, Yk, Yv, Xp, A, SUMB, SQB);
    norm_xT<<<NPOS / 64, 256, 0, stream>>>(A, SUMB, SQB, ln1_w, ln1_b, Xp);

    // ---- stage 2: column attention (attend over S within each column l) ----
    conv_w<<<(wn4 + 255) / 256, 256, 0, stream>>>(col_w, Wh, wn4);
    zero_stats<<<2 * NPOS / 1024, 256, 0, stream>>>(SUMB);
    qkv_gemm_f16<<<ggrid, 512, 0, stream>>>(Wh, col_b, Xp, Yq, Yk, Yv);
    // A = Xp2 + col_out, col-major [d][pos2]
    mfma_attn<SS, false><<<NH * LL, 256, 0, stream>>>(Yq, Yk, Yv, Xp, A, SUMB, SQB);
    norm_transpose<<<DCH * (LL / 32) * (SS / 32), 256, 0, stream>>>(
        A, SUMB, SQB, ln2_w, ln2_b, out, LL, SS);
}

// Round 10
// 318.999 us; speedup vs baseline: 1.0277x; 1.0277x over previous
//
#include <hip/hip_runtime.h>
#include <math.h>

#define DCH 384
#define NH 12
#define CH 32
#define SS 128
#define LL 256
#define NPOS 32768        // SS*LL
#define THREE_D 1152

typedef _Float16 f16_t;
typedef _Float16 f16x4 __attribute__((ext_vector_type(4)));
typedef _Float16 f16x8 __attribute__((ext_vector_type(8)));
typedef float f32x4 __attribute__((ext_vector_type(4)));

// async global->LDS, 16B per lane.
#define GLD16(gptr, lptr) __builtin_amdgcn_global_load_lds( \
    (const __attribute__((address_space(1))) unsigned int*)(gptr), \
    (__attribute__((address_space(3))) unsigned int*)(lptr), 16, 0, 0)

#define WAVE_LDS_FENCE() __asm__ volatile("s_waitcnt lgkmcnt(0)" ::: "memory")

// ---------------------------------------------------------------------------
// fp32 -> fp16 elementwise (weights, layout preserved). n4 = count/4.
// R10: also zeroes the SUM/SQ stats block (2*NPOS floats) in its first
// 16384 threads — replaces the standalone zero_stats dispatches. Safe by
// stream order: stage-1 conv_w precedes the attn atomics; stage-2 conv_w
// runs after norm_xT consumed the previous stats.
// ---------------------------------------------------------------------------
__global__ __launch_bounds__(256) void conv_w(const float* __restrict__ in,
                                              f16_t* __restrict__ out, int n4,
                                              float* __restrict__ stats) {
    int i = blockIdx.x * 256 + threadIdx.x;
    if (i < n4) {
        float4 v = ((const float4*)in)[i];
        unsigned short u0 = __builtin_bit_cast(unsigned short, (f16_t)v.x);
        unsigned short u1 = __builtin_bit_cast(unsigned short, (f16_t)v.y);
        unsigned short u2 = __builtin_bit_cast(unsigned short, (f16_t)v.z);
        unsigned short u3 = __builtin_bit_cast(unsigned short, (f16_t)v.w);
        uint2 r;
        r.x = (unsigned)u0 | ((unsigned)u1 << 16);
        r.y = (unsigned)u2 | ((unsigned)u3 << 16);
        ((uint2*)out)[i] = r;
    }
    if (i < 2 * NPOS / 4)
        ((float4*)stats)[i] = (float4){0.f, 0.f, 0.f, 0.f};
}

// ---------------------------------------------------------------------------
// fp32 [DCH][NPOS] -> fp16 [NPOS][DCH]  (transpose + convert, 64x64 tiles)
// ---------------------------------------------------------------------------
__global__ __launch_bounds__(256) void conv_xT(const float* __restrict__ in,
                                               f16_t* __restrict__ outp) {
    __shared__ float tile[64][65];
    const int p0 = blockIdx.x * 64;
    const int k0 = blockIdx.y * 64;
    const int tx = threadIdx.x & 63, ty = threadIdx.x >> 6;  // ty 0..3
#pragma unroll
    for (int i = 0; i < 16; ++i)
        tile[ty * 16 + i][tx] = in[(size_t)(k0 + ty * 16 + i) * NPOS + p0 + tx];
    __syncthreads();
    const int pr = threadIdx.x >> 2;   // 0..63 output row (p)
    const int cg = threadIdx.x & 3;    // 16-col group (k)
    union { uint4 v[2]; unsigned int u[8]; } res;
#pragma unroll
    for (int j = 0; j < 8; ++j) {
        unsigned short lo = __builtin_bit_cast(unsigned short, (f16_t)tile[cg * 16 + 2 * j][pr]);
        unsigned short hi = __builtin_bit_cast(unsigned short, (f16_t)tile[cg * 16 + 2 * j + 1][pr]);
        res.u[j] = (unsigned)lo | ((unsigned)hi << 16);
    }
    uint4* dst = (uint4*)&outp[(size_t)(p0 + pr) * DCH + k0 + cg * 16];
    dst[0] = res.v[0];
    dst[1] = res.v[1];
}

// ---------------------------------------------------------------------------
// fp16 MFMA GEMM — best measured configuration (R8, 58.4 us / 323.5 total):
// whole 128x384 A panel in LDS once (96 KB), barrier-free K-loop, B streamed
// global->reg DEPTH-2 (depth-4 was null, R9), acc[8][2] (16 MFMA per 2
// B-loads), bijective XCD swizzle, conflict-free row&15 key.
// Falsified levers (do not revisit): shallow-prefetch latency, bank
// conflicts, counted-vmcnt, LDS-pipe pressure, occupancy, depth-4 prefetch.
// ---------------------------------------------------------------------------
__global__ __launch_bounds__(512) void qkv_gemm_f16(
        const f16_t* __restrict__ Wh,    // [THREE_D][DCH]
        const float* __restrict__ bias,  // [THREE_D]
        const f16_t* __restrict__ Xp,    // [NPOS][DCH]
        f16_t* __restrict__ Yq, f16_t* __restrict__ Yk, f16_t* __restrict__ Yv)
{
    __shared__ f16_t sha[128 * 384];   // 96 KB; [row][slot^key] 16B slots
    const int tid  = threadIdx.x;
    const int lane = tid & 63;
    const int wave = tid >> 6;         // 0..7

    // Bijective XCD swizzle: nwg = 9*128 = 1152 = 8 * 144.
    const int hwid = blockIdx.y * 9 + blockIdx.x;      // x fastest in dispatch
    const int nid  = (hwid & 7) * 144 + (hwid >> 3);
    const int ot   = nid % 9;                           // 0..8
    const int pt   = nid / 9;                           // 0..127
    const int o0 = ot * 128;
    const int p0 = pt * 256;

    const int mrow = lane & 15;
    const int kgq  = lane >> 4;        // k-quad 0..3

    // ---- stage whole A panel (128 rows x 48 slots of 16B), once ----
    // slot s of row holds k-group g = s ^ (row & 15) (XOR involution).
#pragma unroll
    for (int j = 0; j < 12; ++j) {
        const int ibase = (wave * 12 + j) * 64;   // wave-uniform slot base
        const int i = ibase + lane;
        const int row = i / 48;
        const int s = i - row * 48;
        const int g = s ^ (row & 15);
        GLD16(Wh + (size_t)(o0 + row) * DCH + g * 8, sha + (size_t)ibase * 8);
    }

    // ---- B reg-stream bases (per-lane). Wave covers p rows wave*32..+31. ----
    const f16_t* bp0 = Xp + (size_t)(p0 + wave * 32 + mrow) * DCH + kgq * 8;
    const f16_t* bp1 = bp0 + (size_t)16 * DCH;

    f32x4 acc[8][2] = {};
    f16x8 breg[3][2];

    // prefetch B tiles 0,1 while A staging drains
    breg[0][0] = *(const f16x8*)(bp0);
    breg[0][1] = *(const f16x8*)(bp1);
    breg[1][0] = *(const f16x8*)(bp0 + 32);
    breg[1][1] = *(const f16x8*)(bp1 + 32);

    __syncthreads();   // the ONLY barrier: A panel visible to all waves

    constexpr int NK = DCH / 32;       // 12
#pragma unroll
    for (int t = 0; t < NK; ++t) {
        if (t + 2 < NK) {
            breg[(t + 2) % 3][0] = *(const f16x8*)(bp0 + (t + 2) * 32);
            breg[(t + 2) % 3][1] = *(const f16x8*)(bp1 + (t + 2) * 32);
        }
        // read rows are mi*16 + mrow -> key = mrow for all mi
        const int soff = ((t * 4 + kgq) ^ mrow) * 8;
#pragma unroll
        for (int mi = 0; mi < 8; ++mi) {
            const f16x8 a = *(const f16x8*)(
                sha + (size_t)(mi * 16 + mrow) * DCH + soff);
            acc[mi][0] = __builtin_amdgcn_mfma_f32_16x16x32_f16(
                a, breg[t % 3][0], acc[mi][0], 0, 0, 0);
            acc[mi][1] = __builtin_amdgcn_mfma_f32_16x16x32_f16(
                a, breg[t % 3][1], acc[mi][1], 0, 0, 0);
        }
    }

    // C/D layout: col = lane&15 (p), row = (lane>>4)*4 + r (o)
    const int col = lane & 15;
    const int rq4 = (lane >> 4) * 4;
    const int qkv = ot / 3;     // 0=q 1=k 2=v
    const int grp = ot % 3;     // 128-block within the qkv group

    if (qkv < 2) {
        f16_t* Yt = (qkv == 0) ? Yq : Yk;
#pragma unroll
        for (int mi = 0; mi < 8; ++mi) {
            const int h  = grp * 4 + (mi >> 1);
            const int cb = (mi & 1) * 16 + rq4;               // c base; +r consecutive
            const int ob = o0 + mi * 16 + rq4;                // bias base
            const float b0 = bias[ob], b1 = bias[ob + 1];
            const float b2 = bias[ob + 2], b3 = bias[ob + 3];
#pragma unroll
            for (int ni = 0; ni < 2; ++ni) {
                const int p = p0 + wave * 32 + ni * 16 + col;
                union { uint2 u; f16_t h4[4]; } w;
                w.h4[0] = (f16_t)(acc[mi][ni][0] + b0);
                w.h4[1] = (f16_t)(acc[mi][ni][1] + b1);
                w.h4[2] = (f16_t)(acc[mi][ni][2] + b2);
                w.h4[3] = (f16_t)(acc[mi][ni][3] + b3);
                *(uint2*)(Yt + ((size_t)h * NPOS + p) * CH + cb) = w.u;
            }
        }
    } else {
#pragma unroll
        for (int mi = 0; mi < 8; ++mi) {
#pragma unroll
            for (int r = 0; r < 4; ++r) {
                const int cg = grp * 128 + mi * 16 + rq4 + r;  // 0..383
                const float br = bias[768 + cg];
#pragma unroll
                for (int ni = 0; ni < 2; ++ni) {
                    const int p = p0 + wave * 32 + ni * 16 + col;
                    Yv[(size_t)cg * NPOS + p] = (f16_t)(acc[mi][ni][r] + br);
                }
            }
        }
    }
}

// ---------------------------------------------------------------------------
// MFMA axial attention, LDS-staged K/V. Fused LN partial stats.
// Residual always fp16 [pos][DCH]. AROW selects A-output layout:
//   AROW=true  (stage 1): A[pos][DCH] coalesced -> row-permute norm_xT.
//   AROW=false (stage 2): A[d][NPOS] -> coalesced norm_transpose.
// ---------------------------------------------------------------------------
template <int SEQ, bool AROW>
__global__ __launch_bounds__(256) void mfma_attn(
        const f16_t* __restrict__ Yq, const f16_t* __restrict__ Yk,
        const f16_t* __restrict__ Yv, const f16_t* __restrict__ Xh,
        f16_t* __restrict__ R, float* __restrict__ SUM, float* __restrict__ SQ)
{
    constexpr int JT  = SEQ / 16;    // j-tiles
    constexpr int NIT = SEQ / 64;    // i-tiles per wave
    constexpr int PST = SEQ + 8;     // padded P row stride (fp16 units)
    constexpr int VST = SEQ + 8;     // padded V row stride
    __shared__ f16_t Ks[SEQ * CH];       // [pos][ch-swz]
    __shared__ f16_t Vs[CH * VST];       // [ch][pos]
    __shared__ f16_t pb[4][16 * PST];
    const int tid  = threadIdx.x;
    const int lane = tid & 63;
    const int wave = tid >> 6;
    const int col = lane & 15, quad = lane >> 4;
    const int h = blockIdx.x % NH;
    const size_t pbase = (size_t)(blockIdx.x / NH) * SEQ;

    const f16_t* qg = Yq + ((size_t)h * NPOS + pbase) * CH;
    const f16_t* kg = Yk + ((size_t)h * NPOS + pbase) * CH;
    const f16_t* vg = Yv + (size_t)h * CH * NPOS + pbase;
    f16_t* mypb = pb[wave];

    // ---- stage K (async, linear dest; source k-group pre-swizzled) ----
    {
        const int ksw = (lane & 3) ^ ((lane >> 3) & 3);
        const int lrow32 = (lane >> 2) * 32;
#pragma unroll
        for (int i = 0; i < SEQ / 64; ++i) {
            const int off = (wave * (SEQ / 64) + i) * 512;  // f16 units
            GLD16(kg + off + lrow32 + ksw * 8, Ks + off);
        }
    }
    // ---- stage V^T (coalesced float4, padded rows) ----
    {
        constexpr int CPR = SEQ / 8;
        const int vch = tid % CPR;
        const int vr0 = tid / CPR;
#pragma unroll
        for (int r = vr0; r < CH; r += 256 / CPR)
            *(float4*)(Vs + r * VST + vch * 8) =
                *(const float4*)(vg + (size_t)r * NPOS + vch * 8);
    }
    __syncthreads();

    const int kq8 = (quad ^ ((col >> 1) & 3)) * 8;   // swizzled Ks k-slot

    for (int it = 0; it < NIT; ++it) {
        const int i0 = (wave * NIT + it) * 16;
        const f16x8 qf = *(const f16x8*)(qg + (size_t)(i0 + col) * CH + quad * 8);
        f32x4 st[JT];
#pragma unroll
        for (int mt = 0; mt < JT; ++mt) {
            f16x8 kf = *(const f16x8*)(Ks + (mt * 16 + col) * CH + kq8);
            st[mt] = __builtin_amdgcn_mfma_f32_16x16x32_f16(kf, qf, (f32x4){0.f, 0.f, 0.f, 0.f}, 0, 0, 0);
        }
        float sum = 0.f;
#pragma unroll
        for (int mt = 0; mt < JT; ++mt)
#pragma unroll
            for (int r = 0; r < 4; ++r) {
                st[mt][r] = __expf(st[mt][r]);
                sum += st[mt][r];
            }
        sum += __shfl_xor(sum, 16, 64);
        sum += __shfl_xor(sum, 32, 64);
        const float inv = 1.f / sum;
#pragma unroll
        for (int mt = 0; mt < JT; ++mt) {
            union { uint2 u; f16_t h4[4]; } w;
            w.h4[0] = (f16_t)(st[mt][0] * inv);
            w.h4[1] = (f16_t)(st[mt][1] * inv);
            w.h4[2] = (f16_t)(st[mt][2] * inv);
            w.h4[3] = (f16_t)(st[mt][3] * inv);
            *(uint2*)(mypb + col * PST + mt * 16 + quad * 4) = w.u;
        }
        WAVE_LDS_FENCE();

        f32x4 o0a = {0.f, 0.f, 0.f, 0.f}, o0b = {0.f, 0.f, 0.f, 0.f};
        f32x4 o1a = {0.f, 0.f, 0.f, 0.f}, o1b = {0.f, 0.f, 0.f, 0.f};
#pragma unroll
        for (int ks = 0; ks < SEQ / 32; ks += 2) {
            f16x8 pf0 = *(const f16x8*)(mypb + col * PST + ks * 32 + quad * 8);
            f16x8 pf1 = *(const f16x8*)(mypb + col * PST + (ks + 1) * 32 + quad * 8);
            f16x8 va0 = *(const f16x8*)(Vs + col * VST + ks * 32 + quad * 8);
            f16x8 va1 = *(const f16x8*)(Vs + col * VST + (ks + 1) * 32 + quad * 8);
            f16x8 vb0 = *(const f16x8*)(Vs + (16 + col) * VST + ks * 32 + quad * 8);
            f16x8 vb1 = *(const f16x8*)(Vs + (16 + col) * VST + (ks + 1) * 32 + quad * 8);
            o0a = __builtin_amdgcn_mfma_f32_16x16x32_f16(va0, pf0, o0a, 0, 0, 0);
            o0b = __builtin_amdgcn_mfma_f32_16x16x32_f16(va1, pf1, o0b, 0, 0, 0);
            o1a = __builtin_amdgcn_mfma_f32_16x16x32_f16(vb0, pf0, o1a, 0, 0, 0);
            o1b = __builtin_amdgcn_mfma_f32_16x16x32_f16(vb1, pf1, o1b, 0, 0, 0);
        }
        const f32x4 ot0 = o0a + o0b;
        const f32x4 ot1 = o1a + o1b;

        const size_t pos = pbase + i0 + col;
        const f16x4 xa = *(const f16x4*)(Xh + pos * DCH + h * CH + quad * 4);
        const f16x4 xb = *(const f16x4*)(Xh + pos * DCH + h * CH + 16 + quad * 4);
        float a0[4], a1[4];
#pragma unroll
        for (int r = 0; r < 4; ++r) {
            a0[r] = (float)xa[r] + ot0[r];
            a1[r] = (float)xb[r] + ot1[r];
        }
        float psum = 0.f, psq = 0.f;
#pragma unroll
        for (int r = 0; r < 4; ++r) {
            psum += a0[r] + a1[r];
            psq  += a0[r] * a0[r] + a1[r] * a1[r];
        }
        if constexpr (AROW) {
            f16x4 w0, w1;
#pragma unroll
            for (int r = 0; r < 4; ++r) {
                w0[r] = (f16_t)a0[r];
                w1[r] = (f16_t)a1[r];
            }
            *(f16x4*)(R + pos * DCH + h * CH + quad * 4)      = w0;
            *(f16x4*)(R + pos * DCH + h * CH + 16 + quad * 4) = w1;
        } else {
#pragma unroll
            for (int r = 0; r < 4; ++r) {
                R[(size_t)(h * CH + quad * 4 + r) * NPOS + pos]      = (f16_t)a0[r];
                R[(size_t)(h * CH + 16 + quad * 4 + r) * NPOS + pos] = (f16_t)a1[r];
            }
        }
        // cross-quad reduce (col fixed): full 32-channel partial for this head
        psum += __shfl_xor(psum, 16, 64);
        psum += __shfl_xor(psum, 32, 64);
        psq  += __shfl_xor(psq, 16, 64);
        psq  += __shfl_xor(psq, 32, 64);
        if (quad == 0) {
            atomicAdd(&SUM[pos], psum);
            atomicAdd(&SQ[pos], psq);
        }
    }
}

// ---------------------------------------------------------------------------
// norm_xT: pure row-permute LN-apply. A fp16 [pos1 = s*LL+l][DCH] ->
// Xp fp16 [pos2 = l*SS+s][DCH]. No transpose, no LDS.
// ---------------------------------------------------------------------------
__global__ __launch_bounds__(256) void norm_xT(
        const f16_t* __restrict__ A, const float* __restrict__ SUM,
        const float* __restrict__ SQ, const float* __restrict__ w,
        const float* __restrict__ b, f16_t* __restrict__ Xp) {
    const int row = blockIdx.x * 64 + (threadIdx.x >> 2);   // pos1
    const int c4 = threadIdx.x & 3;
    const int s = row >> 8, l = row & (LL - 1);             // pos1 = s*LL + l
    const int po = l * SS + s;                              // pos2
    const float m  = SUM[row] * (1.f / DCH);
    const float rs = rsqrtf(SQ[row] * (1.f / DCH) - m * m + 1e-5f);
    const f16_t* ar = A + (size_t)row * DCH;
    f16_t* xr = Xp + (size_t)po * DCH;
#pragma unroll
    for (int j = 0; j < 12; ++j) {
        const int d0 = c4 * 8 + j * 32;
        f16x8 v = *(const f16x8*)(ar + d0);
        const float4 w0 = *(const float4*)(w + d0);
        const float4 w1 = *(const float4*)(w + d0 + 4);
        const float4 b0 = *(const float4*)(b + d0);
        const float4 b1 = *(const float4*)(b + d0 + 4);
        f16x8 o;
        o[0] = (f16_t)(((float)v[0] - m) * rs * w0.x + b0.x);
        o[1] = (f16_t)(((float)v[1] - m) * rs * w0.y + b0.y);
        o[2] = (f16_t)(((float)v[2] - m) * rs * w0.z + b0.z);
        o[3] = (f16_t)(((float)v[3] - m) * rs * w0.w + b0.w);
        o[4] = (f16_t)(((float)v[4] - m) * rs * w1.x + b1.x);
        o[5] = (f16_t)(((float)v[5] - m) * rs * w1.y + b1.y);
        o[6] = (f16_t)(((float)v[6] - m) * rs * w1.z + b1.z);
        o[7] = (f16_t)(((float)v[7] - m) * rs * w1.w + b1.w);
        *(f16x8*)(xr + d0) = o;
    }
}

// ---------------------------------------------------------------------------
// Final: normalize (inline mu/rs from SUM/SQ) + per-channel transpose.
// in is fp16 A [d][pos2-domain]; out fp32. (Both sides coalesced.)
// ---------------------------------------------------------------------------
__global__ __launch_bounds__(256) void norm_transpose(
        const f16_t* __restrict__ in, const float* __restrict__ SUM,
        const float* __restrict__ SQ, const float* __restrict__ w,
        const float* __restrict__ b, float* __restrict__ out, int Rr, int Cc) {
    __shared__ float tile[32][33];
    const int ntc = Cc >> 5, ntr = Rr >> 5;
    int tc = blockIdx.x % ntc;
    int tr = (blockIdx.x / ntc) % ntr;
    int d = blockIdx.x / (ntc * ntr);
    int tx = threadIdx.x & 31, ty = threadIdx.x >> 5;  // ty 0..7
    const f16_t* ip = in + (size_t)d * Rr * Cc;
    float* op = out + (size_t)d * Rr * Cc;
    const float wd = w[d], bd = b[d];
#pragma unroll
    for (int i = 0; i < 32; i += 8) {
        const int r = tr * 32 + ty + i;
        const int c = tc * 32 + tx;
        const int pos = r * Cc + c;
        const float m  = SUM[pos] * (1.f / DCH);
        const float rs = rsqrtf(SQ[pos] * (1.f / DCH) - m * m + 1e-5f);
        float v = (float)ip[(size_t)r * Cc + c];
        tile[ty + i][tx] = (v - m) * rs * wd + bd;
    }
    __syncthreads();
#pragma unroll
    for (int i = 0; i < 32; i += 8)
        op[(size_t)(tc * 32 + ty + i) * Rr + tr * 32 + tx] = tile[tx][ty + i];
}

extern "C" void kernel_launch(void* const* d_in, const int* in_sizes, int n_in,
                              void* d_out, int out_size, void* d_ws, size_t ws_size,
                              hipStream_t stream) {
    const float* x     = (const float*)d_in[0];
    const float* row_w = (const float*)d_in[1];
    const float* row_b = (const float*)d_in[2];
    const float* col_w = (const float*)d_in[3];
    const float* col_b = (const float*)d_in[4];
    const float* ln1_w = (const float*)d_in[5];
    const float* ln1_b = (const float*)d_in[6];
    const float* ln2_w = (const float*)d_in[7];
    const float* ln2_b = (const float*)d_in[8];
    float* out = (float*)d_out;

    char* ws = (char*)d_ws;
    const size_t ysz = (size_t)NH * NPOS * CH * 2;   // 25.2 MB (== DCH*NPOS*2)
    const size_t abytes = (size_t)DCH * NPOS * 4;    // region kept (A uses half)
    f16_t* Yq = (f16_t*)ws;
    f16_t* Yk = (f16_t*)(ws + ysz);
    f16_t* Yv = (f16_t*)(ws + 2 * ysz);
    f16_t* A  = (f16_t*)(ws + 3 * ysz);              // fp16, 25.2 MB
    f16_t* Xp = (f16_t*)(ws + 3 * ysz + abytes);
    f16_t* Wh = (f16_t*)(ws + 3 * ysz + abytes + ysz);
    float* SUMB = (float*)(ws + 3 * ysz + abytes + ysz + (1 << 21));
    float* SQB  = SUMB + NPOS;

    dim3 ggrid(THREE_D / 128, NPOS / 256);   // x = o-tile (9), y = p-tile (128)
    const int wn4 = THREE_D * DCH / 4;
    dim3 cgrid(NPOS / 64, DCH / 64);

    // ---- stage 1: row attention (attend over L within each row s) ----
    conv_w<<<(wn4 + 255) / 256, 256, 0, stream>>>(row_w, Wh, wn4, SUMB);
    conv_xT<<<cgrid, 256, 0, stream>>>(x, Xp);
    qkv_gemm_f16<<<ggrid, 512, 0, stream>>>(Wh, row_b, Xp, Yq, Yk, Yv);
    // A = Xp + row_out, row-major [pos1][DCH]
    mfma_attn<LL, true><<<NH * SS, 256, 0, stream>>>(Yq, Yk, Yv, Xp, A, SUMB, SQB);
    norm_xT<<<NPOS / 64, 256, 0, stream>>>(A, SUMB, SQB, ln1_w, ln1_b, Xp);

    // ---- stage 2: column attention (attend over S within each column l) ----
    conv_w<<<(wn4 + 255) / 256, 256, 0, stream>>>(col_w, Wh, wn4, SUMB);
    qkv_gemm_f16<<<ggrid, 512, 0, stream>>>(Wh, col_b, Xp, Yq, Yk, Yv);
    // A = Xp2 + col_out, col-major [d][pos2]
    mfma_attn<SS, false><<<NH * LL, 256, 0, stream>>>(Yq, Yk, Yv, Xp, A, SUMB, SQB);
    norm_transpose<<<DCH * (LL / 32) * (SS / 32), 256, 0, stream>>>(
        A, SUMB, SQB, ln2_w, ln2_b, out, LL, SS);
}